// Round 1
// baseline (653.904 us; speedup 1.0000x reference)
//
#include <hip/hip_runtime.h>
#include <hip/hip_bf16.h>

#define U_CNT 100000
#define I_CNT 50000
#define N_CNT 150000   // U + I
#define K_DIM 64
#define E_CNT 500000
#define F_DIM 64
#define N_LAYERS 3
#define B_CNT 100000
#define NBLK_SCAN ((N_CNT + 255) / 256)   // 586
#define EP_TILES (E_CNT / 16)             // 31250 (exact)
#define EP_BLOCKS 2048                    // 8 blocks/CU -> 32 waves/CU (was 512 = 2 waves/SIMD)

typedef __hip_bfloat16 bf16;
typedef __attribute__((ext_vector_type(8))) short short8;
typedef __attribute__((ext_vector_type(8))) unsigned short u16x8;
typedef __attribute__((ext_vector_type(4))) float f32x4;

__device__ __forceinline__ float u2f(unsigned short u) {
    return __uint_as_float(((unsigned)u) << 16);
}
__device__ __forceinline__ unsigned short f2u(float x) {
    bf16 h = __float2bfloat16(x);           // RNE
    return *reinterpret_cast<unsigned short*>(&h);
}

// --- int degree count over both endpoints -----------------------------------
__global__ __launch_bounds__(256) void cnt_kernel(const int* __restrict__ rows,
                                                  const int* __restrict__ cols,
                                                  int* __restrict__ cnt) {
    int e = blockIdx.x * blockDim.x + threadIdx.x;
    if (e < E_CNT) {
        atomicAdd(&cnt[rows[e]], 1);
        atomicAdd(&cnt[cols[e]], 1);
    }
}

// --- dinv[n] = deg>0 ? rsqrt(deg) : 0 ---------------------------------------
__global__ __launch_bounds__(256) void dinv_kernel(const int* __restrict__ cnt,
                                                   float* __restrict__ dinv) {
    int n = blockIdx.x * blockDim.x + threadIdx.x;
    if (n < N_CNT) {
        int c = cnt[n];
        dinv[n] = (c > 0) ? rsqrtf((float)c) : 0.0f;
    }
}

// --- hierarchical exclusive scan --------------------------------------------
__global__ __launch_bounds__(256) void scanA_kernel(const int* __restrict__ cnt,
                                                    int* __restrict__ bsum) {
    __shared__ int sd[256];
    int tid = threadIdx.x;
    int i = blockIdx.x * 256 + tid;
    sd[tid] = (i < N_CNT) ? cnt[i] : 0;
    __syncthreads();
    for (int off = 128; off > 0; off >>= 1) {
        if (tid < off) sd[tid] += sd[tid + off];
        __syncthreads();
    }
    if (tid == 0) bsum[blockIdx.x] = sd[0];
}

__global__ __launch_bounds__(1024) void scanB_kernel(const int* __restrict__ bsum,
                                                     int* __restrict__ boff) {
    __shared__ int sd[1024];
    int tid = threadIdx.x;
    int v = (tid < NBLK_SCAN) ? bsum[tid] : 0;
    sd[tid] = v;
    __syncthreads();
    for (int off = 1; off < 1024; off <<= 1) {
        int t = 0;
        if (tid >= off) t = sd[tid - off];
        __syncthreads();
        if (tid >= off) sd[tid] += t;
        __syncthreads();
    }
    if (tid < NBLK_SCAN) boff[tid] = sd[tid] - v;
}

__global__ __launch_bounds__(256) void scanC_kernel(const int* __restrict__ cnt,
                                                    const int* __restrict__ boff,
                                                    int* __restrict__ offs,
                                                    int* __restrict__ cursor) {
    __shared__ int sd[256];
    int tid = threadIdx.x;
    int i = blockIdx.x * 256 + tid;
    int v = (i < N_CNT) ? cnt[i] : 0;
    sd[tid] = v;
    __syncthreads();
    for (int off = 1; off < 256; off <<= 1) {
        int t = 0;
        if (tid >= off) t = sd[tid - off];
        __syncthreads();
        if (tid >= off) sd[tid] += t;
        __syncthreads();
    }
    if (i < N_CNT) {
        int ex = boff[blockIdx.x] + sd[tid] - v;
        offs[i] = ex;
        cursor[i] = ex;
    }
    if (blockIdx.x == 0 && tid == 0) offs[N_CNT] = 2 * E_CNT;
}

// --- scatter directed edges into CSR slots, 16B packed records --------------
// rec = { src byte-offset (src*128), epw byte-offset (eid*128), w bits, 0 }
// One dwordx4 load in prop replaces 3 separate index loads.
__global__ __launch_bounds__(256) void scatter_kernel(const int* __restrict__ rows,
                                                      const int* __restrict__ cols,
                                                      const float* __restrict__ dinv,
                                                      int* __restrict__ cursor,
                                                      int4* __restrict__ erec) {
    int d = blockIdx.x * blockDim.x + threadIdx.x;
    if (d >= 2 * E_CNT) return;
    int eid = (d < E_CNT) ? d : d - E_CNT;
    int src = (d < E_CNT) ? rows[eid] : cols[eid];
    int dst = (d < E_CNT) ? cols[eid] : rows[eid];
    int pos = atomicAdd(&cursor[dst], 1);
    int4 rec;
    rec.x = src << 7;                 // src * K_DIM * sizeof(bf16)
    rec.y = eid << 7;                 // eid * K_DIM * sizeof(bf16)
    rec.z = __float_as_int(dinv[src] * dinv[dst]);
    rec.w = 0;
    erec[pos] = rec;
}

// --- edge projection via MFMA: epw = (ef @ W + b) * nrm, bf16 ---------------
// 16-edge x 64-col tiles; K=F=64 as 2 mfma_f32_16x16x32_bf16 steps.
__global__ __launch_bounds__(256) void ep_kernel(const float* __restrict__ ef,
                                                 const float* __restrict__ W,
                                                 const float* __restrict__ bias,
                                                 const int* __restrict__ rows,
                                                 const int* __restrict__ cols,
                                                 const float* __restrict__ dinv,
                                                 bf16* __restrict__ epw) {
    int lane = threadIdx.x & 63;
    int wv = threadIdx.x >> 6;
    int m15 = lane & 15;
    int quad = lane >> 4;

    short8 bfrag[2][4];
    #pragma unroll
    for (int s = 0; s < 2; s++) {
        #pragma unroll
        for (int t = 0; t < 4; t++) {
            short8 b;
            #pragma unroll
            for (int j = 0; j < 8; j++) {
                int f = s * 32 + quad * 8 + j;
                b[j] = (short)f2u(W[f * K_DIM + t * 16 + m15]);
            }
            bfrag[s][t] = b;
        }
    }
    float bv[4];
    #pragma unroll
    for (int t = 0; t < 4; t++) bv[t] = bias[t * 16 + m15];

    for (int tile = blockIdx.x * 4 + wv; tile < EP_TILES; tile += EP_BLOCKS * 4) {
        int e0 = tile * 16;
        float wlane = 0.0f;
        if (lane < 16) {
            int e = e0 + lane;
            wlane = dinv[rows[e]] * dinv[cols[e]];
        }
        float wrow[4];
        #pragma unroll
        for (int r = 0; r < 4; r++) wrow[r] = __shfl(wlane, quad * 4 + r, 64);

        short8 afrag[2];
        #pragma unroll
        for (int s = 0; s < 2; s++) {
            const float* src = ef + (size_t)(e0 + m15) * F_DIM + s * 32 + quad * 8;
            float4 lo = *(const float4*)src;
            float4 hi = *(const float4*)(src + 4);
            short8 a;
            a[0] = (short)f2u(lo.x); a[1] = (short)f2u(lo.y);
            a[2] = (short)f2u(lo.z); a[3] = (short)f2u(lo.w);
            a[4] = (short)f2u(hi.x); a[5] = (short)f2u(hi.y);
            a[6] = (short)f2u(hi.z); a[7] = (short)f2u(hi.w);
            afrag[s] = a;
        }

        f32x4 acc[4];
        #pragma unroll
        for (int t = 0; t < 4; t++) acc[t] = (f32x4){0.0f, 0.0f, 0.0f, 0.0f};
        #pragma unroll
        for (int s = 0; s < 2; s++) {
            #pragma unroll
            for (int t = 0; t < 4; t++) {
                acc[t] = __builtin_amdgcn_mfma_f32_16x16x32_bf16(
                    afrag[s], bfrag[s][t], acc[t], 0, 0, 0);
            }
        }
        #pragma unroll
        for (int t = 0; t < 4; t++) {
            #pragma unroll
            for (int r = 0; r < 4; r++) {
                int e = e0 + quad * 4 + r;
                float v = (acc[t][r] + bv[t]) * wrow[r];
                epw[(size_t)e * K_DIM + t * 16 + m15] = __float2bfloat16(v);
            }
        }
    }
}

// --- init bf16 tables, vectorized -------------------------------------------
__global__ __launch_bounds__(256) void init_kernel(const float4* __restrict__ Gu,
                                                   const float4* __restrict__ Gi,
                                                   const float4* __restrict__ Gut,
                                                   const float4* __restrict__ Git,
                                                   ushort4* __restrict__ C,
                                                   ushort4* __restrict__ T) {
    int idx = blockIdx.x * blockDim.x + threadIdx.x;
    const int UK4 = U_CNT * K_DIM / 4;
    const int NK4 = N_CNT * K_DIM / 4;
    if (idx >= NK4) return;
    float4 c = (idx < UK4) ? Gu[idx] : Gi[idx - UK4];
    float4 t = (idx < UK4) ? Gut[idx] : Git[idx - UK4];
    ushort4 co, to;
    co.x = f2u(c.x); co.y = f2u(c.y); co.z = f2u(c.z); co.w = f2u(c.w);
    to.x = f2u(t.x); to.y = f2u(t.y); to.z = f2u(t.z); to.w = f2u(t.w);
    C[idx] = co;
    T[idx] = to;
}

// --- one propagation layer: 8 edges per iteration ---------------------------
// Wave per destination node; sub = lane>>3 selects edge slot, q = lane&7 is a
// 16B (8 bf16) chunk of the 128B row. vs the 4-edge version: 2x memory-level
// parallelism per round, E[rounds] 2.0 -> 1.27 (user deg~5, item deg~10), and
// one dwordx4 record load replaces 3 index loads. Next-round record load is
// issued before the FMAs so its latency hides under the gather wait.
__global__ __launch_bounds__(256) void prop_kernel(const int* __restrict__ offs,
                                                   const int4* __restrict__ erec,
                                                   const bf16* __restrict__ epw,
                                                   const bf16* __restrict__ Cin,
                                                   const bf16* __restrict__ Tin,
                                                   bf16* __restrict__ Cout,
                                                   bf16* __restrict__ Tout) {
    int gt = blockIdx.x * blockDim.x + threadIdx.x;
    int n = gt >> 6;
    if (n >= N_CNT) return;
    int lane = threadIdx.x & 63;
    int sub = lane >> 3;
    int q = lane & 7;
    int p0 = offs[n];
    int p1 = offs[n + 1];
    const char* cbase = (const char*)Cin + (q << 4);
    const char* tbase = (const char*)Tin + (q << 4);
    const char* ebase = (const char*)epw + (q << 4);
    float accC[8] = {0.0f, 0.0f, 0.0f, 0.0f, 0.0f, 0.0f, 0.0f, 0.0f};
    float accT[8] = {0.0f, 0.0f, 0.0f, 0.0f, 0.0f, 0.0f, 0.0f, 0.0f};

    int p = p0 + sub;
    int4 r = {0, 0, 0, 0};
    if (p < p1) r = erec[p];
    while (p < p1) {
        u16x8 cv = *(const u16x8*)(cbase + r.x);
        u16x8 tv = *(const u16x8*)(tbase + r.x);
        u16x8 ev = *(const u16x8*)(ebase + r.y);
        float w = __int_as_float(r.z);
        int pn = p + 8;
        if (pn < p1) r = erec[pn];      // prefetch next record under gather wait
        #pragma unroll
        for (int j = 0; j < 8; j++) {
            accC[j] = fmaf(w, u2f(cv[j]), accC[j]);
            accT[j] = fmaf(u2f(ev[j]), u2f(tv[j]), accT[j]);
        }
        p = pn;
    }
    // reduce across the 8 edge slots (sub): lanes sub*8+q -> lane q
    #pragma unroll
    for (int j = 0; j < 8; j++) {
        accC[j] += __shfl_down(accC[j], 32, 64);
        accT[j] += __shfl_down(accT[j], 32, 64);
        accC[j] += __shfl_down(accC[j], 16, 64);
        accT[j] += __shfl_down(accT[j], 16, 64);
        accC[j] += __shfl_down(accC[j], 8, 64);
        accT[j] += __shfl_down(accT[j], 8, 64);
    }
    if (lane < 8) {
        u16x8 oc, ot;
        #pragma unroll
        for (int j = 0; j < 8; j++) {
            oc[j] = f2u(accC[j]);
            ot[j] = f2u(accT[j]);
        }
        *(u16x8*)((char*)Cout + ((size_t)n << 7) + (q << 4)) = oc;
        *(u16x8*)((char*)Tout + ((size_t)n << 7) + (q << 4)) = ot;
    }
}

// --- scoring: wave per query, 64-lane shuffle reduction ---------------------
__global__ __launch_bounds__(256) void score_kernel(const int* __restrict__ users,
                                                    const int* __restrict__ items,
                                                    const bf16* __restrict__ C,
                                                    const bf16* __restrict__ T,
                                                    const float* __restrict__ Bu,
                                                    const float* __restrict__ Bi,
                                                    const float* __restrict__ But,
                                                    const float* __restrict__ Bit,
                                                    const float* __restrict__ Mu,
                                                    float* __restrict__ out) {
    int gt = blockIdx.x * blockDim.x + threadIdx.x;
    int b = gt >> 6;
    int k = threadIdx.x & 63;
    if (b >= B_CNT) return;
    int u = users[b];
    int it = items[b];
    size_t ui = (size_t)u * K_DIM + k;
    size_t ii = (size_t)(U_CNT + it) * K_DIM + k;
    float v = __bfloat162float(C[ui]) * __bfloat162float(C[ii])
            + __bfloat162float(T[ui]) * __bfloat162float(T[ii]);
    #pragma unroll
    for (int off = 32; off > 0; off >>= 1) {
        v += __shfl_down(v, off, 64);
    }
    if (k == 0) {
        v += Bu[u] + Bi[it] + But[u] + Bit[it] + Mu[0];
        out[b] = v;
    }
}

extern "C" void kernel_launch(void* const* d_in, const int* in_sizes, int n_in,
                              void* d_out, int out_size, void* d_ws, size_t ws_size,
                              hipStream_t stream) {
    const float* Gu   = (const float*)d_in[0];
    const float* Gi   = (const float*)d_in[1];
    const float* Gut  = (const float*)d_in[2];
    const float* Git  = (const float*)d_in[3];
    const float* Bu   = (const float*)d_in[4];
    const float* Bi   = (const float*)d_in[5];
    const float* But  = (const float*)d_in[6];
    const float* Bit  = (const float*)d_in[7];
    const float* Mu   = (const float*)d_in[8];
    const float* W    = (const float*)d_in[9];
    const float* bpj  = (const float*)d_in[10];
    const float* ef   = (const float*)d_in[11];
    const int* rows   = (const int*)d_in[12];
    const int* cols   = (const int*)d_in[13];
    const int* users  = (const int*)d_in[14];
    const int* items  = (const int*)d_in[15];
    float* out = (float*)d_out;

    const size_t NK = (size_t)N_CNT * K_DIM;
    const size_t EK = (size_t)E_CNT * K_DIM;

    char* wp = (char*)d_ws;
    auto alloc = [&](size_t bytes) {
        char* r = wp;
        wp += (bytes + 255) & ~(size_t)255;
        return r;
    };
    bf16* epw    = (bf16*)alloc(EK * sizeof(bf16));              // 64 MB
    bf16* C0     = (bf16*)alloc(NK * sizeof(bf16));              // 19.2 MB
    bf16* C1     = (bf16*)alloc(NK * sizeof(bf16));
    bf16* T0     = (bf16*)alloc(NK * sizeof(bf16));
    bf16* T1     = (bf16*)alloc(NK * sizeof(bf16));
    float* dinv  = (float*)alloc(N_CNT * sizeof(float));
    int4* erec   = (int4*)alloc((size_t)(2 * E_CNT + 8) * sizeof(int4)); // 16 MB
    int* cnt     = (int*)alloc(N_CNT * sizeof(int));
    int* offs    = (int*)alloc((N_CNT + 1) * sizeof(int));
    int* cursor  = (int*)alloc(N_CNT * sizeof(int));
    int* bsum    = (int*)alloc(NBLK_SCAN * sizeof(int));
    int* boff    = (int*)alloc(NBLK_SCAN * sizeof(int));

    hipMemsetAsync(cnt, 0, N_CNT * sizeof(int), stream);
    cnt_kernel<<<(E_CNT + 255) / 256, 256, 0, stream>>>(rows, cols, cnt);
    dinv_kernel<<<(N_CNT + 255) / 256, 256, 0, stream>>>(cnt, dinv);
    scanA_kernel<<<NBLK_SCAN, 256, 0, stream>>>(cnt, bsum);
    scanB_kernel<<<1, 1024, 0, stream>>>(bsum, boff);
    scanC_kernel<<<NBLK_SCAN, 256, 0, stream>>>(cnt, boff, offs, cursor);
    scatter_kernel<<<(2 * E_CNT + 255) / 256, 256, 0, stream>>>(
        rows, cols, dinv, cursor, erec);
    ep_kernel<<<EP_BLOCKS, 256, 0, stream>>>(ef, W, bpj, rows, cols, dinv, epw);
    init_kernel<<<((int)(NK / 4) + 255) / 256, 256, 0, stream>>>(
        (const float4*)Gu, (const float4*)Gi, (const float4*)Gut, (const float4*)Git,
        (ushort4*)C0, (ushort4*)T0);

    bf16* Cs[2] = {C0, C1};
    bf16* Ts[2] = {T0, T1};
    int cur = 0;
    for (int l = 0; l < N_LAYERS; l++) {
        prop_kernel<<<(N_CNT * 64 + 255) / 256, 256, 0, stream>>>(
            offs, erec, epw, Cs[cur], Ts[cur], Cs[1 - cur], Ts[1 - cur]);
        cur = 1 - cur;
    }

    score_kernel<<<(B_CNT * 64 + 255) / 256, 256, 0, stream>>>(
        users, items, Cs[cur], Ts[cur], Bu, Bi, But, Bit, Mu, out);
}